// Round 6
// baseline (258.743 us; speedup 1.0000x reference)
//
#include <hip/hip_runtime.h>

// Multibin binary conv:  y = conv2d(sign(x), sum_m sign(W_m), SAME) + sum_m b_m
// x: [16,256,256,32] f32   W: [4,3,3,32,32] f32   b: [4,32] f32 -> out f32
//
// Implicit GEMM, mfma_i32_32x32x32_i8 (exact: signs ±1 i8, wsum {-4..4} i8).
// 1-wave blocks (64 thr), 32-col x 8-row strip, grid 4096.  NO barriers.
// Rows staged ASYNC via global_load_lds (raw f32 ring of 3), packed LDS->LDS
// to i8 im2col (ring of 4), depth-2 pipeline with counted vmcnt waits.
//
// Round-6 changes vs round 4 (85.5 us):
//  1. OPERAND-SWAPPED MFMA: mfma(bfrag, a) -> D col=pixel, row=cout.  Each
//     lane owns 16 couts of ONE pixel in groups of 4 -> epilogue is
//     4x global_store_dwordx4 instead of 16x scalar dword.  Store request
//     count drops 4x (theory: per-CU VMEM request slots are the shared
//     limiter; stores outnumbered read requests 3:1 in every prior round).
//     Steady-state ledger: vmcnt(21) -> vmcnt(9).
//  2. XCD-chunked block swizzle (bid&7)*512 + bid>>3: adjacent rowstrips
//     (25% halo re-read sharing) become same-XCD L2-local.  4096%8==0.

#define RH      8
#define PITCHB  48                    // packed bytes per pixel (32 ci + 16 pad)
#define PSLOT   (34 * PITCHB)         // 1632 B packed row slot (x4)
#define RSLOT   4096                  // raw slot: 32 interior px * 128 B (x3)
#define RAWOFF  (4 * PSLOT)           // packed [0,6528) raw [6528,18816)

typedef __attribute__((ext_vector_type(4)))  int i32x4;
typedef __attribute__((ext_vector_type(16))) int i32x16;

__device__ __forceinline__ void gload16(const void* g, void* l) {
    __builtin_amdgcn_global_load_lds(
        (const __attribute__((address_space(1))) void*)g,
        (__attribute__((address_space(3))) void*)l, 16, 0, 0);
}

__device__ __forceinline__ unsigned packsgn4(uint4 v) {
    unsigned r;
    r  =  (__uint_as_float(v.x) >= 0.0f) ? 0x01u : 0xFFu;
    r |= ((__uint_as_float(v.y) >= 0.0f) ? 0x01u : 0xFFu) << 8;
    r |= ((__uint_as_float(v.z) >= 0.0f) ? 0x01u : 0xFFu) << 16;
    r |= ((__uint_as_float(v.w) >= 0.0f) ? 0x01u : 0xFFu) << 24;
    return r;
}

// ---------------- prep: wsT[co][288] i8 + bsum[32] f32 into d_ws ----------------
__global__ void prep_kernel(const float* __restrict__ W, const float* __restrict__ bias,
                            signed char* __restrict__ wsT, float* __restrict__ bsum) {
    int t = blockIdx.x * 256 + threadIdx.x;
    if (t < 9216) {
        int k   = t >> 5;          // 0..287 = tap*32 + ci
        int co  = t & 31;
        int tap = k >> 5;
        int ci  = k & 31;
        float s = 0.0f;
        #pragma unroll
        for (int m = 0; m < 4; ++m) {
            float w = W[(m * 9 + tap) * 1024 + ci * 32 + co];
            s += (w >= 0.0f) ? 1.0f : -1.0f;
        }
        wsT[co * 288 + k] = (signed char)(int)s;
    }
    if (t < 32) {
        float s = 0.0f;
        #pragma unroll
        for (int m = 0; m < 4; ++m) s += bias[m * 32 + t];
        bsum[t] = s;
    }
}

// counted wait + scheduling fence
#define WAITV(N)                                                                \
    do {                                                                        \
        asm volatile("s_waitcnt vmcnt(" #N ")" ::: "memory");                   \
        __builtin_amdgcn_sched_barrier(0);                                      \
    } while (0)

// halo register select by row index (ring of 3, compile-time)
#define HSEL(J) ((((J) % 3) == 0) ? h0 : ((((J) % 3) == 1) ? h1 : h2))

// issue one row's staging: 4x global_load_lds (interior, swizzled source) +
// 1 per-lane halo dword (issued LAST).  5 VMEM ops exactly.
#define ISSUE_ROW(J, HREG)                                                      \
    do {                                                                        \
        const int row_  = r0 - 1 + (J);                                         \
        const int rowc_ = row_ < 0 ? 0 : (row_ > 255 ? 255 : row_);             \
        const char* gb_ = (const char*)(x + (long)((bimg * 256 + rowc_) * 256   \
                                                   + c0) * 32);                 \
        unsigned char* lb_ = lds + RAWOFF + ((J) % 3) * RSLOT;                  \
        _Pragma("unroll")                                                       \
        for (int k_ = 0; k_ < 4; ++k_)                                          \
            gload16(gb_ + k_ * 1024 + lswz16, lb_ + k_ * 1024);                 \
        HREG = *(x + (long)(bimg * 256 + rowc_) * 8192 + hoff);                 \
        __builtin_amdgcn_sched_barrier(0);                                      \
    } while (0)

// pack row J (raw f32 LDS -> signed i8 im2col LDS).  Halo byte FIRST.
#define PACK_ROW(J, HREG)                                                       \
    do {                                                                        \
        const int row_   = r0 - 1 + (J);                                        \
        const bool rowok_ = (row_ >= 0) && (row_ < 256);                        \
        unsigned char* ps_ = lds + ((J) & 3) * PSLOT;                           \
        const unsigned char* rs_ = lds + RAWOFF + ((J) % 3) * RSLOT;            \
        ps_[hpx * PITCHB + (lane & 31)] =                                       \
            (rowok_ && hok) ? ((HREG >= 0.0f) ? 0x01 : 0xFF) : 0;               \
        uint4 o_;                                                               \
        if (rowok_) {                                                           \
            uint4 w0_ = *(const uint4*)(rs_ + (ppx * 8 + ((ph * 4 + 0) ^ pxr)) * 16); \
            uint4 w1_ = *(const uint4*)(rs_ + (ppx * 8 + ((ph * 4 + 1) ^ pxr)) * 16); \
            uint4 w2_ = *(const uint4*)(rs_ + (ppx * 8 + ((ph * 4 + 2) ^ pxr)) * 16); \
            uint4 w3_ = *(const uint4*)(rs_ + (ppx * 8 + ((ph * 4 + 3) ^ pxr)) * 16); \
            o_ = make_uint4(packsgn4(w0_), packsgn4(w1_),                       \
                            packsgn4(w2_), packsgn4(w3_));                      \
        } else {                                                                \
            o_ = make_uint4(0u, 0u, 0u, 0u);                                    \
        }                                                                       \
        *(uint4*)(ps_ + (ppx + 1) * PITCHB + ph * 16) = o_;                     \
    } while (0)

__global__ __launch_bounds__(64, 2) void conv_kernel(const float* __restrict__ x,
                                                     const signed char* __restrict__ wsT,
                                                     const float* __restrict__ bsum,
                                                     float* __restrict__ out) {
    __shared__ __align__(16) unsigned char lds[4 * PSLOT + 3 * RSLOT];  // 18816 B

    const int lane = threadIdx.x;     // single wave per block
    const int lrow = lane & 31;       // bfrag: cout row / a: pixel / D: pixel col
    const int lk   = lane >> 5;       // K-half selector

    // XCD-chunked swizzle: XCD k (= bid%8) gets orig chunk [k*512,(k+1)*512)
    // -> adjacent rowstrips (halo sharers) live on the same XCD's L2.
    const int bid  = blockIdx.x;
    const int bs   = (bid & 7) * 512 + (bid >> 3);
    const int c0   = (bs & 7) * 32;
    const int r0   = ((bs >> 3) & 31) * RH;
    const int bimg = bs >> 8;

    // B fragments + bias first: retire under prologue waits
    i32x4 bfrag[9];
    #pragma unroll
    for (int t = 0; t < 9; ++t)
        bfrag[t] = *(const i32x4*)(wsT + lrow * 288 + t * 32 + lk * 16);
    // lane's 16 accs map to couts (reg&3) + 8*(reg>>2) + 4*lk
    const float4 bias0 = *(const float4*)(bsum + 0  + 4 * lk);
    const float4 bias1 = *(const float4*)(bsum + 8  + 4 * lk);
    const float4 bias2 = *(const float4*)(bsum + 16 + 4 * lk);
    const float4 bias3 = *(const float4*)(bsum + 24 + 4 * lk);

    // geometry
    const int lswz16 = (lane ^ ((lane >> 3) & 7)) * 16;   // global-side pre-swizzle
    const int hcol   = (lane < 32) ? (c0 > 0 ? c0 - 1 : 0)
                                   : (c0 + 32 < 256 ? c0 + 32 : 255);
    const bool hok   = (lane < 32) ? (c0 > 0) : (c0 + 32 < 256);
    const int  hpx   = (lane < 32) ? 0 : 33;
    const long hoff  = (long)hcol * 32 + (lane & 31);     // in floats
    const int  ppx   = lane >> 1;                         // pack: pixel 0..31
    const int  ph    = lane & 1;                          // pack: ci half
    const int  pxr   = ppx & 7;                           // raw read de-swizzle

    float h0 = 0.f, h1 = 0.f, h2 = 0.f;

    // ---- prologue: rows j0..j2 async, packed under counted waits ----
    // (counted-from-tail: N leaves the N newest outstanding, so the extra
    //  bias loads ahead of j0 don't change the numbers)
    ISSUE_ROW(0, HSEL(0));
    ISSUE_ROW(1, HSEL(1));
    ISSUE_ROW(2, HSEL(2));
    WAITV(10);  PACK_ROW(0, HSEL(0));
    WAITV(5);   PACK_ROW(1, HSEL(1));
    ISSUE_ROW(3, HSEL(3));
    WAITV(5);   PACK_ROW(2, HSEL(2));

    const int a_off = lrow * PITCHB + lk * 16;

    #pragma unroll
    for (int i = 0; i < RH; ++i) {
        // issue row j=i+4 (rows j0..j9 total)
        if (i <= RH - 3) ISSUE_ROW(i + 4, HSEL(i + 4));

        // wait for row j=i+3's DMA (one full iteration old); stores + fresh
        // loads stay outstanding.  Ledger (4-wide stores now):
        //   i=0: [j4:5] -> 5    i=1..5: [stores:4][j:5] -> 9    i=6: [stores:4] -> 4
        if (i == 0)      { WAITV(5); }
        else if (i == 1) { WAITV(9); }
        else if (i == 2) { WAITV(9); }
        else if (i == 3) { WAITV(9); }
        else if (i == 4) { WAITV(9); }
        else if (i == 5) { WAITV(9); }
        else if (i == 6) { WAITV(4); }
        if (i <= RH - 2) PACK_ROW(i + 3, HSEL(i + 3));

        // ---- MFMA (operand-swapped): D[row=cout][col=pixel] ----
        i32x16 acc = {};
        #pragma unroll
        for (int dh = 0; dh < 3; ++dh) {
            const unsigned char* sb = lds + ((i + dh) & 3) * PSLOT + a_off;
            #pragma unroll
            for (int dw = 0; dw < 3; ++dw) {
                i32x4 a = *(const i32x4*)(sb + dw * PITCHB);
                acc = __builtin_amdgcn_mfma_i32_32x32x32_i8(bfrag[dh * 3 + dw],
                                                            a, acc, 0, 0, 0);
            }
        }

        // ---- store: lane owns pixel (lane&31); acc[4q+j] = cout q*8+4*lk+j
        //      -> 4x global_store_dwordx4 (vs 16 scalar) ----
        float* op = out + ((long)((bimg * 256 + (r0 + i)) * 256 + c0 + lrow)) * 32
                    + 4 * lk;
        *(float4*)(op + 0)  = make_float4((float)acc[0]  + bias0.x,
                                          (float)acc[1]  + bias0.y,
                                          (float)acc[2]  + bias0.z,
                                          (float)acc[3]  + bias0.w);
        *(float4*)(op + 8)  = make_float4((float)acc[4]  + bias1.x,
                                          (float)acc[5]  + bias1.y,
                                          (float)acc[6]  + bias1.z,
                                          (float)acc[7]  + bias1.w);
        *(float4*)(op + 16) = make_float4((float)acc[8]  + bias2.x,
                                          (float)acc[9]  + bias2.y,
                                          (float)acc[10] + bias2.z,
                                          (float)acc[11] + bias2.w);
        *(float4*)(op + 24) = make_float4((float)acc[12] + bias3.x,
                                          (float)acc[13] + bias3.y,
                                          (float)acc[14] + bias3.z,
                                          (float)acc[15] + bias3.w);
    }
}

extern "C" void kernel_launch(void* const* d_in, const int* in_sizes, int n_in,
                              void* d_out, int out_size, void* d_ws, size_t ws_size,
                              hipStream_t stream) {
    const float* x    = (const float*)d_in[0];   // [16,256,256,32]
    const float* W    = (const float*)d_in[1];   // [4,3,3,32,32]
    const float* bias = (const float*)d_in[2];   // [4,32]
    float* out = (float*)d_out;

    signed char* wsT = (signed char*)d_ws;              // 9216 B
    float* bsum = (float*)((char*)d_ws + 9216);         // 32 f32

    prep_kernel<<<36, 256, 0, stream>>>(W, bias, wsT, bsum);
    conv_kernel<<<4096, 64, 0, stream>>>(x, wsT, bsum, out);
}